// Round 9
// baseline (2584.336 us; speedup 1.0000x reference)
//
#include <hip/hip_runtime.h>
#include <hip/hip_bf16.h>

// ---------------------------------------------------------------------------
// BottleneckVQa. Encoder fp32 (argmin stability; summation order preserved).
// conv1: r0 tiled-LDS direct conv. conv2 (conv5s2_q2): deep pipeline fitted
// to 128 VGPR / 16 waves/CU — launch_bounds(256,4); KYBODY split into row
// halves (transient x-quads 32->16 VGPR). x: depth-2 reg prefetch over
// triple-buffered LDS; w: global b128 ky-ping-pong. r8's (256,3) capped at
// 84 VGPR -> 3GB scratch spill; this pins the only viable operating point.
// ---------------------------------------------------------------------------

#define DEV_INLINE __device__ __forceinline__

typedef __attribute__((ext_vector_type(8))) short bf16x8;
typedef __attribute__((ext_vector_type(4))) float f32x4;

#define GLL16(g, l) __builtin_amdgcn_global_load_lds(                      \
    (const __attribute__((address_space(1))) void*)(g),                    \
    (__attribute__((address_space(3))) void*)(l), 16, 0, 0)

DEV_INLINE float gelu_exact(float v) {
    return 0.5f * v * (1.0f + erff(v * 0.70710678118654752440f));
}

// ---- weight transpose to [c][tap][oc] fp32 (oc=64) ----
__global__ void wtf_k(const float* __restrict__ w, float* __restrict__ wt,
                      int C, int total) {
    int t = blockIdx.x * 256 + threadIdx.x;
    if (t >= total) return;
    int oc = t & 63;
    int rest = t >> 6;
    int tap = rest % 25, c = rest / 25;
    wt[t] = w[(oc * C + c) * 25 + tap];
}

// ---- conv k5 s2 p2 + gelu, 64 oc (conv1: 2x2 pos x 16 oc, r0 variant) ----
template<int C, int IH, int IW>
__global__ __launch_bounds__(256) void conv5s2_t(
    const float* __restrict__ xg,
    const float* __restrict__ wt,   // [C][25][64]
    float* __restrict__ outg) {     // [32][64][IH/2][IW/2]
    constexpr int OH = IH / 2, OW = IW / 2;
    __shared__ float xin[35 * 36];
    __shared__ float wl[1600];
    const int tid = threadIdx.x;
    const int n = blockIdx.z;
    const int OY0 = blockIdx.y * 16, OX0 = blockIdx.x * 16;
    const int IY0 = OY0 * 2 - 2, IX0 = OX0 * 2 - 2;
    const int og = tid & 3;          // oc group: oc = og*16 + q*4 + {0..3}
    const int pg = tid >> 2;         // 64 position groups (8x8 of 2x2)
    const int py = (pg >> 3) * 2, px = (pg & 7) * 2;
    const int ry = py * 2, rx = px * 2;  // input-local base

    f32x4 a00 = {0,0,0,0}, a01 = a00, a02 = a00, a03 = a00;
    f32x4 a10 = a00, a11 = a00, a12 = a00, a13 = a00;
    f32x4 a20 = a00, a21 = a00, a22 = a00, a23 = a00;
    f32x4 a30 = a00, a31 = a00, a32 = a00, a33 = a00;

    const float* xn = xg + (size_t)n * C * IH * IW;
    for (int c = 0; c < C; ++c) {
        {   // stage weights for channel c: 1600 floats
            const float4* wsrc = (const float4*)(wt + c * 1600);
            float4* wdst = (float4*)wl;
            wdst[tid] = wsrc[tid];
            if (tid < 144) wdst[256 + tid] = wsrc[256 + tid];
        }
        const float* zc = xn + (size_t)c * IH * IW;
        for (int i = tid; i < 1225; i += 256) {
            int r = i / 35, cl = i - r * 35;
            int iy = IY0 + r, ix = IX0 + cl;
            float v = 0.f;
            if ((unsigned)iy < (unsigned)IH && (unsigned)ix < (unsigned)IW)
                v = zc[(size_t)iy * IW + ix];
            xin[r * 36 + cl] = v;
        }
        __syncthreads();
#pragma unroll
        for (int ky = 0; ky < 5; ++ky) {
            const float* r0 = xin + (ry + ky) * 36 + rx;
            const float* r1 = r0 + 72;
#pragma unroll
            for (int kx = 0; kx < 5; ++kx) {
                const f32x4* wq = (const f32x4*)(wl + (ky * 5 + kx) * 64 + og * 16);
                f32x4 w0 = wq[0], w1 = wq[1], w2 = wq[2], w3 = wq[3];
                float xA = r0[kx], xB = r0[kx + 2];
                float xC = r1[kx], xD = r1[kx + 2];
                a00 += xA * w0; a01 += xA * w1; a02 += xA * w2; a03 += xA * w3;
                a10 += xB * w0; a11 += xB * w1; a12 += xB * w2; a13 += xB * w3;
                a20 += xC * w0; a21 += xC * w1; a22 += xC * w2; a23 += xC * w3;
                a30 += xD * w0; a31 += xD * w1; a32 += xD * w2; a33 += xD * w3;
            }
        }
        __syncthreads();
    }
    const int ocb = og * 16;
#define CSTORE(v, oy, ox, q) {                                                \
        float* o = outg + (((size_t)n * 64 + ocb + (q) * 4) * OH + (oy)) * OW \
                   + (ox);                                                    \
        o[0]               = gelu_exact((v).x);                               \
        o[(size_t)OH * OW]     = gelu_exact((v).y);                           \
        o[(size_t)2 * OH * OW] = gelu_exact((v).z);                           \
        o[(size_t)3 * OH * OW] = gelu_exact((v).w); }
    CSTORE(a00, OY0 + py,     OX0 + px,     0); CSTORE(a01, OY0 + py,     OX0 + px,     1);
    CSTORE(a02, OY0 + py,     OX0 + px,     2); CSTORE(a03, OY0 + py,     OX0 + px,     3);
    CSTORE(a10, OY0 + py,     OX0 + px + 1, 0); CSTORE(a11, OY0 + py,     OX0 + px + 1, 1);
    CSTORE(a12, OY0 + py,     OX0 + px + 1, 2); CSTORE(a13, OY0 + py,     OX0 + px + 1, 3);
    CSTORE(a20, OY0 + py + 1, OX0 + px,     0); CSTORE(a21, OY0 + py + 1, OX0 + px,     1);
    CSTORE(a22, OY0 + py + 1, OX0 + px,     2); CSTORE(a23, OY0 + py + 1, OX0 + px,     3);
    CSTORE(a30, OY0 + py + 1, OX0 + px + 1, 0); CSTORE(a31, OY0 + py + 1, OX0 + px + 1, 1);
    CSTORE(a32, OY0 + py + 1, OX0 + px + 1, 2); CSTORE(a33, OY0 + py + 1, OX0 + px + 1, 3);
#undef CSTORE
}

// ---- conv2: pipelined, fitted to 128 VGPR. 8x16 tile; lane = 2r x 4c x 4oc.
// x: loads for ch c+2 issued at iter c (regs), LDS-written at iter c+1,
// read at iter c+2 — triple-buffered LDS, ONE barrier/channel.
// w: global per-lane b128, ky+1 ping-pong prefetch. KYBODY split into row
// halves (per-accumulator FMA chain order unchanged -> z2 bitwise stable).
template<int C, int IH, int IW>
__global__ __launch_bounds__(256, 4) void conv5s2_q2(
    const float* __restrict__ xg,
    const float* __restrict__ wt,   // [C][25][64]
    float* __restrict__ outg) {     // [32][64][IH/2][IW/2]
    constexpr int OH = IH / 2, OW = IW / 2;
    __shared__ float xp[3 * 760];    // 3 bufs x [2 planes][19 rows][20 cols]
    const int tid = threadIdx.x;
    const int n = blockIdx.z;
    const int OY0 = blockIdx.y * 8, OX0 = blockIdx.x * 16;
    const int IY0 = OY0 * 2 - 2, IX0 = OX0 * 2 - 2;
    const int og = tid & 15;         // oc = og*4 + j
    const int pg = tid >> 4;
    const int py = (pg >> 2) * 2;    // out row base {0,2,4,6}
    const int px = (pg & 3) * 4;     // out col base {0,4,8,12}
    const int ry = py * 2;           // input-local row base

    // hoisted staging slots: 684 elems (19 rows x 36 cols); slots tid,
    // tid+256, tid+512 (only tid<172)
    int sG0, sG1, sG2, sL0, sL1, sL2;
    bool sIn0, sIn1, sIn2;
    const bool sWr2 = (tid < 172);
    {
        int s = tid;       int r = s / 36, cl = s - r * 36;
        int iy = IY0 + r,  ix = IX0 + cl;
        sIn0 = ((unsigned)iy < (unsigned)IH) && ((unsigned)ix < (unsigned)IW);
        sG0 = sIn0 ? (iy * IW + ix) : 0;
        sL0 = (cl & 1) * 380 + r * 20 + (cl >> 1);
        s = tid + 256;     r = s / 36; cl = s - r * 36;
        iy = IY0 + r;      ix = IX0 + cl;
        sIn1 = ((unsigned)iy < (unsigned)IH) && ((unsigned)ix < (unsigned)IW);
        sG1 = sIn1 ? (iy * IW + ix) : 0;
        sL1 = (cl & 1) * 380 + r * 20 + (cl >> 1);
        s = tid + 512;     r = s / 36; cl = s - r * 36;
        iy = IY0 + r;      ix = IX0 + cl;
        sIn2 = sWr2 && ((unsigned)iy < (unsigned)IH) &&
               ((unsigned)ix < (unsigned)IW);
        sG2 = sIn2 ? (iy * IW + ix) : 0;
        sL2 = sWr2 ? ((cl & 1) * 380 + r * 20 + (cl >> 1)) : 0;
    }

    const float* xn = xg + (size_t)n * C * IH * IW;
    const float* wtb = wt + og * 4;  // per-lane weight base

    float xr0, xr1, xr2;
#define XLOAD(cc) { const float* zc = xn + (size_t)(cc) * IH * IW;          \
        xr0 = sIn0 ? zc[sG0] : 0.f;                                         \
        xr1 = sIn1 ? zc[sG1] : 0.f;                                         \
        xr2 = sIn2 ? zc[sG2] : 0.f; }
#define XWRITE(bw) { float* xw = xp + (bw) * 760;                           \
        xw[sL0] = xr0; xw[sL1] = xr1; if (sWr2) xw[sL2] = xr2; }

    f32x4 a00 = {0,0,0,0}, a01 = a00, a02 = a00, a03 = a00;
    f32x4 a10 = a00, a11 = a00, a12 = a00, a13 = a00;
    f32x4 wA0, wA1, wA2, wA3, wA4, wB0, wB1, wB2, wB3, wB4;
#define WLOAD(P, cc, ky) {                                                  \
        const float* wp = wtb + (size_t)(cc) * 1600 + (ky) * 320;           \
        P##0 = *(const f32x4*)(wp);       P##1 = *(const f32x4*)(wp + 64);  \
        P##2 = *(const f32x4*)(wp + 128); P##3 = *(const f32x4*)(wp + 192); \
        P##4 = *(const f32x4*)(wp + 256); }

#define PICK8(Qa, Qb, i) ((i) < 4 ? (Qa)[(i) & 3] : (Qb)[(i) & 3])
#define XVR(kx, jj) (((kx) & 1) ? PICK8(P0, P1, (jj) + ((kx) >> 1))         \
                                : PICK8(Q0, Q1, (jj) + ((kx) >> 1)))
// one output row: 4 quads live, 20 FMAs; per-acc chain order = kx ascending
#define KYROW(base, A0_, A1_, A2_, A3_, W) {                                \
        const float* e_ = (base);                                           \
        const f32x4 Q0 = *(const f32x4*)e_;                                 \
        const f32x4 Q1 = *(const f32x4*)(e_ + 4);                           \
        const f32x4 P0 = *(const f32x4*)(e_ + 380);                         \
        const f32x4 P1 = *(const f32x4*)(e_ + 384);                         \
        _Pragma("unroll")                                                   \
        for (int kx = 0; kx < 5; ++kx) {                                    \
            const f32x4 wv = (kx == 0) ? W##0 : (kx == 1) ? W##1            \
                           : (kx == 2) ? W##2 : (kx == 3) ? W##3 : W##4;    \
            float xA = XVR(kx, 0), xB = XVR(kx, 1);                         \
            float xC = XVR(kx, 2), xD = XVR(kx, 3);                         \
            A0_ += xA * wv; A1_ += xB * wv; A2_ += xC * wv; A3_ += xD * wv; \
        } }
#define KYBODY(ky, W) {                                                     \
        const float* e0 = xb + (ry + (ky)) * 20 + px;                       \
        KYROW(e0,      a00, a01, a02, a03, W)                               \
        KYROW(e0 + 40, a10, a11, a12, a13, W) }

    // prologue: ch0 -> LDS buf0; ch1 loads in flight; w(0,ky0) in flight
    XLOAD(0)
    XWRITE(0)
    XLOAD(1)
    WLOAD(wA, 0, 0)

    int br = 0;                      // compute(c) reads buf br = c%3
    for (int c = 0; c < C; ++c) {
        const int bw = (br + 1 >= 3) ? br + 1 - 3 : br + 1;
        XWRITE(bw)                   // ch c+1 (loads issued 1 iter ago)
        if (c + 2 < C) XLOAD(c + 2)  // issue next-next channel loads
        __syncthreads();
        const float* xb = xp + br * 760;
        const int cn = (c + 1 < C) ? (c + 1) : c;
        if ((c & 1) == 0) {
            WLOAD(wB, c, 1)  KYBODY(0, wA)
            WLOAD(wA, c, 2)  KYBODY(1, wB)
            WLOAD(wB, c, 3)  KYBODY(2, wA)
            WLOAD(wA, c, 4)  KYBODY(3, wB)
            WLOAD(wB, cn, 0) KYBODY(4, wA)
        } else {
            WLOAD(wA, c, 1)  KYBODY(0, wB)
            WLOAD(wB, c, 2)  KYBODY(1, wA)
            WLOAD(wA, c, 3)  KYBODY(2, wB)
            WLOAD(wB, c, 4)  KYBODY(3, wA)
            WLOAD(wA, cn, 0) KYBODY(4, wB)
        }
        br = bw;
    }
#undef KYBODY
#undef KYROW
#undef XVR
#undef PICK8
#undef WLOAD
#undef XWRITE
#undef XLOAD

    const size_t HW = (size_t)OH * OW;
#pragma unroll
    for (int j = 0; j < 4; ++j) {
        float* o = outg + ((size_t)n * 64 + og * 4 + j) * HW
                   + (size_t)(OY0 + py) * OW + (OX0 + px);
        f32x4 t0, t1;
        t0[0] = gelu_exact(a00[j]); t0[1] = gelu_exact(a01[j]);
        t0[2] = gelu_exact(a02[j]); t0[3] = gelu_exact(a03[j]);
        t1[0] = gelu_exact(a10[j]); t1[1] = gelu_exact(a11[j]);
        t1[2] = gelu_exact(a12[j]); t1[3] = gelu_exact(a13[j]);
        *(f32x4*)o = t0;
        *(f32x4*)(o + OW) = t1;
    }
}

// ---- conv3: [32,64,64,64] -> [32,64,63,63], k2 s1 p0, fp32 ----
__global__ void conv3_k(const float* __restrict__ z2,
                        const float* __restrict__ w,   // [64,64,2,2]
                        float* __restrict__ z) {
    __shared__ float wl[1024];
    const int oc0 = blockIdx.y * 4;
    for (int i = threadIdx.x; i < 1024; i += 256) {
        int j = i & 3, r = i >> 2;
        wl[i] = w[(oc0 + j) * 256 + r];
    }
    __syncthreads();
    const int s = blockIdx.x * 256 + threadIdx.x;
    if (s >= 3969) return;
    const int n = blockIdx.z;
    const int oy = s / 63, ox = s % 63;
    const float4* wv = (const float4*)wl;
    float a0 = 0.f, a1 = 0.f, a2 = 0.f, a3 = 0.f;
    const float* zn = z2 + n * 64 * 4096;
    for (int c = 0; c < 64; ++c) {
        const float* zc = zn + c * 4096;
#pragma unroll
        for (int tap = 0; tap < 4; ++tap) {
            int iy = oy + (tap >> 1), ix = ox + (tap & 1);
            float xv = zc[iy * 64 + ix];
            float4 wq = wv[c * 4 + tap];
            a0 += xv * wq.x; a1 += xv * wq.y; a2 += xv * wq.z; a3 += xv * wq.w;
        }
    }
    int obase = (n * 64 + oc0) * 3969 + s;
    z[obase]            = a0;
    z[obase + 3969]     = a1;
    z[obase + 2 * 3969] = a2;
    z[obase + 3 * 3969] = a3;
}

// ---- VQ: argmin over 24 codes, z_probs (fp32), commitment loss ----
__global__ void vq_k(const float* __restrict__ z,
                     const float* __restrict__ codes,
                     const float* __restrict__ ema,
                     int* __restrict__ idxO,
                     float* __restrict__ zprobsO,
                     float* __restrict__ lossO) {
    __shared__ float cl[1536];
    __shared__ float cn[24];
    __shared__ float pr[24];
    for (int i = threadIdx.x; i < 1536; i += 256) cl[i] = codes[i];
    if (threadIdx.x < 24) pr[threadIdx.x] = ema[threadIdx.x];
    __syncthreads();
    if (threadIdx.x < 24) {
        float sm = 0.f;
        for (int c = 0; c < 64; ++c) { float v = cl[threadIdx.x * 64 + c]; sm += v * v; }
        cn[threadIdx.x] = sm;
    }
    __syncthreads();
    int t = blockIdx.x * 256 + threadIdx.x;
    float l = 0.f;
    if (t < 127008) {
        int b = t / 3969, s = t - b * 3969;
        const float* zp = z + (b * 64) * 3969 + s;
        float zv[64];
        float zn = 0.f;
#pragma unroll
        for (int c = 0; c < 64; ++c) { float v = zp[c * 3969]; zv[c] = v; zn += v * v; }
        float best = 1e30f; int bi = 0;
        for (int k = 0; k < 24; ++k) {
            float dot = 0.f;
#pragma unroll
            for (int c = 0; c < 64; ++c) dot += zv[c] * cl[k * 64 + c];
            float d = zn - 2.f * dot + cn[k];
            if (d < best) { best = d; bi = k; }
        }
        idxO[t] = bi;
        float psum = 0.f;
        for (int k = 0; k < 24; ++k) psum += pr[k];
        zprobsO[t] = pr[bi] / psum;
        for (int c = 0; c < 64; ++c) { float dd = cl[bi * 64 + c] - zv[c]; l += dd * dd; }
    }
    for (int off = 32; off; off >>= 1) l += __shfl_down(l, off, 64);
    if ((threadIdx.x & 63) == 0) atomicAdd(lossO, l);
}

// ---- D table: D[k][tap][oc] = sum_c codes[k][c] * dec_w1[oc][c][tap] ----
__global__ void dtab_k(const float* __restrict__ codes,
                       const float* __restrict__ w1,  // [512,64,2,2]
                       float* __restrict__ D) {
    int t = blockIdx.x * 256 + threadIdx.x;
    if (t >= 24 * 4 * 512) return;
    int oc = t & 511, tap = (t >> 9) & 3, k = t >> 11;
    float acc = 0.f;
    for (int c = 0; c < 64; ++c)
        acc += codes[k * 64 + c] * w1[oc * 256 + c * 4 + tap];
    D[t] = acc;
}

// ---- weight transform: wT[oc][tap][c] bf16 from w[oc][c][2][2] fp32 ----
__global__ void wt_k(const float* __restrict__ w, __hip_bfloat16* __restrict__ wT,
                     int cl2, int total) {
    int t = blockIdx.x * 256 + threadIdx.x;
    if (t >= total) return;
    int c = t & ((1 << cl2) - 1);
    int tap = (t >> cl2) & 3;
    int oc = t >> (cl2 + 2);
    wT[t] = __float2bfloat16(w[((oc << cl2) + c) * 4 + tap]);
}

// ---- dec1: codebook gather -> y1 NHWC [32][64][64][512] bf16, + gelu ----
__global__ void dec1_k(const int* __restrict__ idx,   // [32,63,63]
                       const float* __restrict__ D,   // [24][4][512]
                       __hip_bfloat16* __restrict__ y1) {
    const int pos = blockIdx.x;
    const int n = pos >> 12, rem = pos & 4095;
    const int iy = rem >> 6, ix = rem & 63;
    const int* idn = idx + n * 3969;
    const int t = threadIdx.x;
    float ax = 0.f, ay = 0.f;
#pragma unroll
    for (int tap = 0; tap < 4; ++tap) {
        int py = iy - 1 + (tap >> 1), px = ix - 1 + (tap & 1);
        if ((unsigned)py < 63u && (unsigned)px < 63u) {
            int k = idn[py * 63 + px];
            float2 v = ((const float2*)(D + (k * 4 + tap) * 512))[t];
            ax += v.x; ay += v.y;
        }
    }
    __hip_bfloat162 o;
    o.x = __float2bfloat16(gelu_exact(ax));
    o.y = __float2bfloat16(gelu_exact(ay));
    ((__hip_bfloat162*)(y1 + (size_t)pos * 512))[t] = o;
}

// ---- dec2 MFMA: C[pos][oc] = sum_k y1im2col[pos][k] * wT2[oc][k] ----
__global__ __launch_bounds__(256) void dec2_mfma(
    const __hip_bfloat16* __restrict__ y1,   // NHWC [32][64][64][512]
    const __hip_bfloat16* __restrict__ wT,   // [256][2048]
    const __hip_bfloat16* __restrict__ zp,   // zero page
    __hip_bfloat16* __restrict__ y2)         // NHWC [32][63][63][256]
{
    __shared__ __hip_bfloat16 As[128 * 32];
    __shared__ __hip_bfloat16 Bs[128 * 32];
    const int tid = threadIdx.x;
    const int wave = tid >> 6, lane = tid & 63;
    const int quad = lane >> 4, l15 = lane & 15;
    const int m0 = blockIdx.x * 128;
    const int oc0 = blockIdx.y * 128;
    const int sub = tid & 3;

    const char* pA[2];
    const char* pB[2];
#pragma unroll
    for (int j = 0; j < 2; ++j) {
        int slot = j * 64 + (tid >> 2);
        int pp = m0 + slot;
        if (pp < 127008) {
            int n = pp / 3969; int r = pp - n * 3969;
            int oy = r / 63;  int ox = r - oy * 63;
            pA[j] = (const char*)y1 + (size_t)((n * 64 + oy) * 64 + ox) * 1024 + sub * 16;
        } else {
            pA[j] = (const char*)zp;
        }
        pB[j] = (const char*)wT + (size_t)(oc0 + slot) * 4096 + sub * 16;
    }
    char* ldsA[2] = {(char*)As + wave * 1024, (char*)As + 4096 + wave * 1024};
    char* ldsB[2] = {(char*)Bs + wave * 1024, (char*)Bs + 4096 + wave * 1024};

    f32x4 acc[4][4] = {};
    const int wm = (wave & 1) * 64;
    const int wn = (wave >> 1) * 64;

#pragma unroll
    for (int tap = 0; tap < 4; ++tap) {
        const int toff = ((tap >> 1) * 64 + (tap & 1)) * 1024;
        for (int kk = 0; kk < 16; ++kk) {
            const int cb = kk * 64;
            GLL16(pA[0] + toff + cb, ldsA[0]);
            GLL16(pA[1] + toff + cb, ldsA[1]);
            GLL16(pB[0] + tap * 1024 + cb, ldsB[0]);
            GLL16(pB[1] + tap * 1024 + cb, ldsB[1]);
            __syncthreads();
            bf16x8 af[4], bf[4];
#pragma unroll
            for (int mi = 0; mi < 4; ++mi)
                af[mi] = *(const bf16x8*)((const char*)As + (wm + mi * 16 + l15) * 64 + quad * 16);
#pragma unroll
            for (int ni = 0; ni < 4; ++ni)
                bf[ni] = *(const bf16x8*)((const char*)Bs + (wn + ni * 16 + l15) * 64 + quad * 16);
#pragma unroll
            for (int mi = 0; mi < 4; ++mi)
#pragma unroll
                for (int ni = 0; ni < 4; ++ni)
                    acc[mi][ni] = __builtin_amdgcn_mfma_f32_16x16x32_bf16(
                        af[mi], bf[ni], acc[mi][ni], 0, 0, 0);
            __syncthreads();
        }
    }
#pragma unroll
    for (int mi = 0; mi < 4; ++mi)
#pragma unroll
        for (int r = 0; r < 4; ++r) {
            int pos = m0 + wm + mi * 16 + quad * 4 + r;
            if (pos < 127008) {
#pragma unroll
                for (int ni = 0; ni < 4; ++ni) {
                    int oc = oc0 + wn + ni * 16 + l15;
                    y2[(size_t)pos * 256 + oc] =
                        __float2bfloat16(gelu_exact(acc[mi][ni][r]));
                }
            }
        }
}

// ---- dec3 MFMA: C[oc][pos] = sum_k wT3[oc][k] * y2im2col[pos][k] ----
__global__ __launch_bounds__(256) void dec3_mfma(
    const __hip_bfloat16* __restrict__ y2,   // NHWC [32][63][63][256]
    const __hip_bfloat16* __restrict__ wT,   // [256][1024]
    const __hip_bfloat16* __restrict__ zp,
    float* __restrict__ out)                 // NCHW [32][256][64][64]
{
    __shared__ __hip_bfloat16 As[128 * 32];
    __shared__ __hip_bfloat16 Bs[128 * 32];
    const int tid = threadIdx.x;
    const int wave = tid >> 6, lane = tid & 63;
    const int quad = lane >> 4, l15 = lane & 15;
    const int p0 = blockIdx.x * 128;
    const int oc0 = blockIdx.y * 128;
    const int sub = tid & 3;

    const char* pW[2];
    const char* pP[4][2];
#pragma unroll
    for (int j = 0; j < 2; ++j) {
        int slot = j * 64 + (tid >> 2);
        pW[j] = (const char*)wT + (size_t)(oc0 + slot) * 2048 + sub * 16;
        int pp = p0 + slot;
        int n = pp >> 12, rem = pp & 4095;
        int OY = rem >> 6, OX = rem & 63;
#pragma unroll
        for (int tap = 0; tap < 4; ++tap) {
            int iy = OY - 1 + (tap >> 1), ix = OX - 1 + (tap & 1);
            if ((unsigned)iy < 63u && (unsigned)ix < 63u)
                pP[tap][j] = (const char*)y2 + (size_t)(n * 3969 + iy * 63 + ix) * 512 + sub * 16;
            else
                pP[tap][j] = (const char*)zp;
        }
    }
    char* ldsA[2] = {(char*)As + wave * 1024, (char*)As + 4096 + wave * 1024};
    char* ldsB[2] = {(char*)Bs + wave * 1024, (char*)Bs + 4096 + wave * 1024};

    f32x4 acc[4][4] = {};
    const int wm = (wave & 1) * 64;
    const int wn = (wave >> 1) * 64;

#pragma unroll
    for (int tap = 0; tap < 4; ++tap) {
        for (int kk = 0; kk < 8; ++kk) {
            const int cb = kk * 64;
            GLL16(pW[0] + tap * 512 + cb, ldsA[0]);
            GLL16(pW[1] + tap * 512 + cb, ldsA[1]);
            GLL16(pP[tap][0] + cb, ldsB[0]);
            GLL16(pP[tap][1] + cb, ldsB[1]);
            __syncthreads();
            bf16x8 af[4], bf[4];
#pragma unroll
            for (int mi = 0; mi < 4; ++mi)
                af[mi] = *(const bf16x8*)((const char*)As + (wm + mi * 16 + l15) * 64 + quad * 16);
#pragma unroll
            for (int ni = 0; ni < 4; ++ni)
                bf[ni] = *(const bf16x8*)((const char*)Bs + (wn + ni * 16 + l15) * 64 + quad * 16);
#pragma unroll
            for (int mi = 0; mi < 4; ++mi)
#pragma unroll
                for (int ni = 0; ni < 4; ++ni)
                    acc[mi][ni] = __builtin_amdgcn_mfma_f32_16x16x32_bf16(
                        af[mi], bf[ni], acc[mi][ni], 0, 0, 0);
            __syncthreads();
        }
    }
    const int n = p0 >> 12;
    const int posLocal0 = (p0 & 4095) + wn;
#pragma unroll
    for (int mi = 0; mi < 4; ++mi)
#pragma unroll
        for (int r = 0; r < 4; ++r) {
            int oc = oc0 + wm + mi * 16 + quad * 4 + r;
            float* orow = out + ((size_t)(n * 256 + oc) << 12);
#pragma unroll
            for (int ni = 0; ni < 4; ++ni)
                orow[posLocal0 + ni * 16 + l15] = acc[mi][ni][r];
        }
}

// ---- scalar: vq_loss = 0.25 * sum / (B*C*H*W) ----
__global__ void loss_k(const float* __restrict__ lossO, float* __restrict__ out) {
    out[0] = 0.25f * lossO[0] / 8128512.0f;
}

extern "C" void kernel_launch(void* const* d_in, const int* in_sizes, int n_in,
                              void* d_out, int out_size, void* d_ws, size_t ws_size,
                              hipStream_t stream) {
    const float* x     = (const float*)d_in[0];
    const float* ew1   = (const float*)d_in[1];
    const float* ew2   = (const float*)d_in[2];
    const float* ew3   = (const float*)d_in[3];
    const float* dw1   = (const float*)d_in[4];
    const float* dw2   = (const float*)d_in[5];
    const float* dw3   = (const float*)d_in[6];
    const float* codes = (const float*)d_in[7];
    const float* ema   = (const float*)d_in[8];
    float* out = (float*)d_out;

    char* ws = (char*)d_ws;
    float* z1   = (float*)(ws + 0);            // [32,64,128,128] f32
    float* z2   = (float*)(ws + 134217728);    // [32,64,64,64]  f32
    float* z    = (float*)(ws + 167772160);    // [32,64,63,63]  f32
    int*   idx  = (int*)  (ws + 200286208);    // [32,63,63]     i32
    float* loss = (float*)(ws + 200794240);    // accumulator
    __hip_bfloat16* zp  = (__hip_bfloat16*)(ws + 200794496);  // 69,632 B zero page
    float* D    = (float*)(ws + 200864128);    // [24,4,512] f32
    __hip_bfloat16* wT2 = (__hip_bfloat16*)(ws + 201650560);  // 1 MB [256][2048]
    __hip_bfloat16* wT3 = (__hip_bfloat16*)(ws + 202699136);  // 512 KB [256][1024]
    // encoder-phase scratch overlapping decoder weight regions (dead until wt_k):
    float* wt2f = (float*)(ws + 201650560);    // 409,600 B [64][25][64]
    float* wt1f = (float*)(ws + 202699136);    //  19,200 B [3][25][64]
    __hip_bfloat16* y1  = (__hip_bfloat16*)(ws + 0);          // reuse z1
    __hip_bfloat16* y2  = (__hip_bfloat16*)(ws + 134217728);  // reuse z2+z

    hipMemsetAsync(loss, 0, 4, stream);
    hipMemsetAsync(zp, 0, 69632, stream);

    wtf_k<<<dim3(19), 256, 0, stream>>>(ew1, wt1f, 3, 4800);
    wtf_k<<<dim3(400), 256, 0, stream>>>(ew2, wt2f, 64, 102400);
    conv5s2_t<3, 256, 256><<<dim3(8, 8, 32), 256, 0, stream>>>(x, wt1f, z1);
    conv5s2_q2<64, 128, 128><<<dim3(4, 8, 32), 256, 0, stream>>>(z1, wt2f, z2);
    conv3_k<<<dim3(16, 16, 32), 256, 0, stream>>>(z2, ew3, z);
    vq_k<<<dim3(497), 256, 0, stream>>>(z, codes, ema, idx, out + 33554432, loss);
    dtab_k<<<dim3(192), 256, 0, stream>>>(codes, dw1, D);
    wt_k<<<dim3(2048), 256, 0, stream>>>(dw2, wT2, 9, 524288);
    wt_k<<<dim3(1024), 256, 0, stream>>>(dw3, wT3, 8, 262144);
    dec1_k<<<dim3(131072), 256, 0, stream>>>(idx, D, y1);
    dec2_mfma<<<dim3(993, 2), 256, 0, stream>>>(y1, wT2, zp, y2);
    dec3_mfma<<<dim3(1024, 2), 256, 0, stream>>>(y2, wT3, zp, out);
    loss_k<<<1, 1, 0, stream>>>(loss, out + 33681440);
}

// Round 10
// 1160.935 us; speedup vs baseline: 2.2261x; 2.2261x over previous
//
#include <hip/hip_runtime.h>
#include <hip/hip_bf16.h>

// ---------------------------------------------------------------------------
// BottleneckVQa. Encoder fp32 (argmin stability; summation order preserved).
// conv1: r0 tiled-LDS direct conv. conv2: r6 conv5s2_g (bench-verified 403us;
// 6 structural variants all plateau 403-418 -> accepted). conv3: NEW
// conv3_t — LDS x-slab + L2 transposed weights, replacing 256 scalar
// loads/thread (537M loads, ~220us issue-bound). VQ; MFMA bf16 decoder.
// ---------------------------------------------------------------------------

#define DEV_INLINE __device__ __forceinline__

typedef __attribute__((ext_vector_type(8))) short bf16x8;
typedef __attribute__((ext_vector_type(4))) float f32x4;

#define GLL16(g, l) __builtin_amdgcn_global_load_lds(                      \
    (const __attribute__((address_space(1))) void*)(g),                    \
    (__attribute__((address_space(3))) void*)(l), 16, 0, 0)

DEV_INLINE float gelu_exact(float v) {
    return 0.5f * v * (1.0f + erff(v * 0.70710678118654752440f));
}

// ---- weight transpose to [c][tap][oc] fp32 (oc=64), k5 convs ----
__global__ void wtf_k(const float* __restrict__ w, float* __restrict__ wt,
                      int C, int total) {
    int t = blockIdx.x * 256 + threadIdx.x;
    if (t >= total) return;
    int oc = t & 63;
    int rest = t >> 6;
    int tap = rest % 25, c = rest / 25;
    wt[t] = w[(oc * C + c) * 25 + tap];
}

// ---- weight transpose for conv3: w[oc][c][2][2] -> wt3[c][tap][oc] ----
__global__ void wtf3_k(const float* __restrict__ w, float* __restrict__ wt3) {
    int t = blockIdx.x * 256 + threadIdx.x;
    if (t >= 16384) return;
    int oc = t & 63, tap = (t >> 6) & 3, c = t >> 8;
    wt3[t] = w[(oc * 64 + c) * 4 + tap];
}

// ---- conv k5 s2 p2 + gelu, 64 oc (conv1: 2x2 pos x 16 oc, r0 variant) ----
template<int C, int IH, int IW>
__global__ __launch_bounds__(256) void conv5s2_t(
    const float* __restrict__ xg,
    const float* __restrict__ wt,   // [C][25][64]
    float* __restrict__ outg) {     // [32][64][IH/2][IW/2]
    constexpr int OH = IH / 2, OW = IW / 2;
    __shared__ float xin[35 * 36];
    __shared__ float wl[1600];
    const int tid = threadIdx.x;
    const int n = blockIdx.z;
    const int OY0 = blockIdx.y * 16, OX0 = blockIdx.x * 16;
    const int IY0 = OY0 * 2 - 2, IX0 = OX0 * 2 - 2;
    const int og = tid & 3;          // oc group: oc = og*16 + q*4 + {0..3}
    const int pg = tid >> 2;         // 64 position groups (8x8 of 2x2)
    const int py = (pg >> 3) * 2, px = (pg & 7) * 2;
    const int ry = py * 2, rx = px * 2;  // input-local base

    f32x4 a00 = {0,0,0,0}, a01 = a00, a02 = a00, a03 = a00;
    f32x4 a10 = a00, a11 = a00, a12 = a00, a13 = a00;
    f32x4 a20 = a00, a21 = a00, a22 = a00, a23 = a00;
    f32x4 a30 = a00, a31 = a00, a32 = a00, a33 = a00;

    const float* xn = xg + (size_t)n * C * IH * IW;
    for (int c = 0; c < C; ++c) {
        {   // stage weights for channel c: 1600 floats
            const float4* wsrc = (const float4*)(wt + c * 1600);
            float4* wdst = (float4*)wl;
            wdst[tid] = wsrc[tid];
            if (tid < 144) wdst[256 + tid] = wsrc[256 + tid];
        }
        const float* zc = xn + (size_t)c * IH * IW;
        for (int i = tid; i < 1225; i += 256) {
            int r = i / 35, cl = i - r * 35;
            int iy = IY0 + r, ix = IX0 + cl;
            float v = 0.f;
            if ((unsigned)iy < (unsigned)IH && (unsigned)ix < (unsigned)IW)
                v = zc[(size_t)iy * IW + ix];
            xin[r * 36 + cl] = v;
        }
        __syncthreads();
#pragma unroll
        for (int ky = 0; ky < 5; ++ky) {
            const float* r0 = xin + (ry + ky) * 36 + rx;
            const float* r1 = r0 + 72;
#pragma unroll
            for (int kx = 0; kx < 5; ++kx) {
                const f32x4* wq = (const f32x4*)(wl + (ky * 5 + kx) * 64 + og * 16);
                f32x4 w0 = wq[0], w1 = wq[1], w2 = wq[2], w3 = wq[3];
                float xA = r0[kx], xB = r0[kx + 2];
                float xC = r1[kx], xD = r1[kx + 2];
                a00 += xA * w0; a01 += xA * w1; a02 += xA * w2; a03 += xA * w3;
                a10 += xB * w0; a11 += xB * w1; a12 += xB * w2; a13 += xB * w3;
                a20 += xC * w0; a21 += xC * w1; a22 += xC * w2; a23 += xC * w3;
                a30 += xD * w0; a31 += xD * w1; a32 += xD * w2; a33 += xD * w3;
            }
        }
        __syncthreads();
    }
    const int ocb = og * 16;
#define CSTORE(v, oy, ox, q) {                                                \
        float* o = outg + (((size_t)n * 64 + ocb + (q) * 4) * OH + (oy)) * OW \
                   + (ox);                                                    \
        o[0]               = gelu_exact((v).x);                               \
        o[(size_t)OH * OW]     = gelu_exact((v).y);                           \
        o[(size_t)2 * OH * OW] = gelu_exact((v).z);                           \
        o[(size_t)3 * OH * OW] = gelu_exact((v).w); }
    CSTORE(a00, OY0 + py,     OX0 + px,     0); CSTORE(a01, OY0 + py,     OX0 + px,     1);
    CSTORE(a02, OY0 + py,     OX0 + px,     2); CSTORE(a03, OY0 + py,     OX0 + px,     3);
    CSTORE(a10, OY0 + py,     OX0 + px + 1, 0); CSTORE(a11, OY0 + py,     OX0 + px + 1, 1);
    CSTORE(a12, OY0 + py,     OX0 + px + 1, 2); CSTORE(a13, OY0 + py,     OX0 + px + 1, 3);
    CSTORE(a20, OY0 + py + 1, OX0 + px,     0); CSTORE(a21, OY0 + py + 1, OX0 + px,     1);
    CSTORE(a22, OY0 + py + 1, OX0 + px,     2); CSTORE(a23, OY0 + py + 1, OX0 + px,     3);
    CSTORE(a30, OY0 + py + 1, OX0 + px + 1, 0); CSTORE(a31, OY0 + py + 1, OX0 + px + 1, 1);
    CSTORE(a32, OY0 + py + 1, OX0 + px + 1, 2); CSTORE(a33, OY0 + py + 1, OX0 + px + 1, 3);
#undef CSTORE
}

// ---- conv2: r6 conv5s2_g (bench-verified 403us) ----
template<int C, int IH, int IW>
__global__ __launch_bounds__(256, 4) void conv5s2_g(
    const float* __restrict__ xg,
    const float* __restrict__ wt,   // [C][25][64]
    float* __restrict__ outg) {     // [32][64][IH/2][IW/2]
    constexpr int OH = IH / 2, OW = IW / 2;
    __shared__ float xp[760];        // [2 planes][19 rows][20 cols]
    const int tid = threadIdx.x;
    const int n = blockIdx.z;
    const int OY0 = blockIdx.y * 8, OX0 = blockIdx.x * 16;
    const int IY0 = OY0 * 2 - 2, IX0 = OX0 * 2 - 2;
    const int og = tid & 15;         // oc = og*4 + j
    const int pg = tid >> 4;         // 16 groups: row-pair (pg>>2), col (pg&3)
    const int py = (pg >> 2) * 2;    // out row base {0,2,4,6}
    const int px = (pg & 3) * 4;     // out col base {0,4,8,12}
    const int ry = py * 2;           // input-local row base {0,4,8,12}

    // hoisted staging slots: 684 elements (19 rows x 36 cols), 3 per thread
    int  sG[3]; int sL[3]; bool sIn[3]; bool sWr[3];
#pragma unroll
    for (int k = 0; k < 3; ++k) {
        int s = tid + k * 256;
        int r = s / 36, cl = s - r * 36;
        int iy = IY0 + r, ix = IX0 + cl;
        sWr[k] = (s < 684);
        sIn[k] = sWr[k] && ((unsigned)iy < (unsigned)IH) &&
                 ((unsigned)ix < (unsigned)IW);
        sG[k] = sIn[k] ? (iy * IW + ix) : 0;
        sL[k] = sWr[k] ? ((cl & 1) * 380 + r * 20 + (cl >> 1)) : 0;
    }

    const float* xn = xg + (size_t)n * C * IH * IW;
    const float* wtb = wt + og * 4;  // per-lane weight base (oc offset)

    f32x4 a00 = {0,0,0,0}, a01 = a00, a02 = a00, a03 = a00;
    f32x4 a10 = a00, a11 = a00, a12 = a00, a13 = a00;

    for (int c = 0; c < C; ++c) {
        const float* zc = xn + (size_t)c * IH * IW;
#pragma unroll
        for (int k = 0; k < 3; ++k) {
            if (sWr[k]) {
                float v = sIn[k] ? zc[sG[k]] : 0.f;
                xp[sL[k]] = v;
            }
        }
        __syncthreads();

        const float* wc = wtb + (size_t)c * 1600;   // [25][64] this channel
#define PICK8(Qa, Qb, i) ((i) < 4 ? (Qa)[(i) & 3] : (Qb)[(i) & 3])
#define XV(R, kx, jj) (((kx) & 1)                                           \
        ? PICK8(O##R##0, O##R##1, (jj) + ((kx) >> 1))                       \
        : PICK8(E##R##0, E##R##1, (jj) + ((kx) >> 1)))
#pragma unroll
        for (int ky = 0; ky < 5; ++ky) {
            // weights for this ky: 5 taps, one f32x4 each (global, L2-hit)
            f32x4 w0 = *(const f32x4*)(wc + (ky * 5 + 0) * 64);
            f32x4 w1 = *(const f32x4*)(wc + (ky * 5 + 1) * 64);
            f32x4 w2 = *(const f32x4*)(wc + (ky * 5 + 2) * 64);
            f32x4 w3 = *(const f32x4*)(wc + (ky * 5 + 3) * 64);
            f32x4 w4 = *(const f32x4*)(wc + (ky * 5 + 4) * 64);
            // x quads for rows R0 = ry+ky, R1 = R0+2, both parity planes
            const float* e0 = xp + (ry + ky) * 20 + px;
            const float* o0 = e0 + 380;
            const float* e1 = e0 + 40;
            const float* o1 = o0 + 40;
            const f32x4 E00 = *(const f32x4*)e0, E01 = *(const f32x4*)(e0 + 4);
            const f32x4 O00 = *(const f32x4*)o0, O01 = *(const f32x4*)(o0 + 4);
            const f32x4 E10 = *(const f32x4*)e1, E11 = *(const f32x4*)(e1 + 4);
            const f32x4 O10 = *(const f32x4*)o1, O11 = *(const f32x4*)(o1 + 4);
#pragma unroll
            for (int kx = 0; kx < 5; ++kx) {
                const f32x4 wv = (kx == 0) ? w0 : (kx == 1) ? w1
                               : (kx == 2) ? w2 : (kx == 3) ? w3 : w4;
                float xA = XV(0, kx, 0), xB = XV(0, kx, 1);
                float xC = XV(0, kx, 2), xD = XV(0, kx, 3);
                float xE = XV(1, kx, 0), xF = XV(1, kx, 1);
                float xG = XV(1, kx, 2), xH = XV(1, kx, 3);
                a00 += xA * wv; a01 += xB * wv; a02 += xC * wv; a03 += xD * wv;
                a10 += xE * wv; a11 += xF * wv; a12 += xG * wv; a13 += xH * wv;
            }
        }
#undef XV
#undef PICK8
        __syncthreads();
    }

    const size_t HW = (size_t)OH * OW;
#pragma unroll
    for (int j = 0; j < 4; ++j) {
        float* o = outg + ((size_t)n * 64 + og * 4 + j) * HW
                   + (size_t)(OY0 + py) * OW + (OX0 + px);
        f32x4 t0, t1;
        t0[0] = gelu_exact(a00[j]); t0[1] = gelu_exact(a01[j]);
        t0[2] = gelu_exact(a02[j]); t0[3] = gelu_exact(a03[j]);
        t1[0] = gelu_exact(a10[j]); t1[1] = gelu_exact(a11[j]);
        t1[2] = gelu_exact(a12[j]); t1[3] = gelu_exact(a13[j]);
        *(f32x4*)o = t0;
        *(f32x4*)(o + OW) = t1;
    }
}

// ---- conv3_t: [32,64,64,64] -> [32,64,63,63], k2 s1 p0, fp32, LDS-tiled --
// Block = (oy, n): stages 2-row x 64-ch x-slab once (36KB LDS, 4 blk/CU);
// weights wt3[c][tap][oc] read as 4-lane-bcast b128 from L2 (64KB hot).
// Per-output chain order (c -> tap0..3) identical to old conv3_k -> z
// bitwise unchanged -> VQ idx/absmax stable. Replaces 256 scalar global
// loads/thread (537M loads total).
__global__ __launch_bounds__(256) void conv3_t(
    const float* __restrict__ z2,
    const float* __restrict__ wt3,   // [64][4][64] fp32
    float* __restrict__ z) {         // [32][64][63][63]
    __shared__ float xs[64 * 144];   // [c][2 rows][72 cols] (64 used + pad)
    const int tid = threadIdx.x;
    const int oy = blockIdx.x;       // 0..62
    const int n  = blockIdx.y;

    {   // stage x-slab: 2048 f32x4, 8 per thread (coalesced 64B runs)
        const float* zn = z2 + (size_t)n * 64 * 4096 + oy * 64;
#pragma unroll
        for (int k = 0; k < 8; ++k) {
            int fid = tid + k * 256;
            int c = fid >> 5, rem = fid & 31;
            int r = rem >> 4, q = rem & 15;
            f32x4 v = *(const f32x4*)(zn + c * 4096 + r * 64 + q * 4);
            *(f32x4*)(xs + c * 144 + r * 72 + q * 4) = v;
        }
    }
    __syncthreads();

    const int og  = tid >> 4;        // 0..15 -> oc = og*4 + {0..3}
    const int ox4 = (tid & 15) * 4;  // 0,4,...,60
    f32x4 a0 = {0,0,0,0}, a1 = a0, a2 = a0, a3 = a0;   // ox4+0..3
    const float* wb = wt3 + og * 4;

    for (int c = 0; c < 64; ++c) {
        const float* xc = xs + c * 144 + ox4;
        const f32x4 X00 = *(const f32x4*)(xc);        // row0 [ox4..+3]
        const f32x4 X01 = *(const f32x4*)(xc + 4);    // row0 [ox4+4..+7]
        const f32x4 X10 = *(const f32x4*)(xc + 72);   // row1
        const f32x4 X11 = *(const f32x4*)(xc + 76);
        const float* wc = wb + c * 256;
        const f32x4 w0 = *(const f32x4*)(wc);         // tap (0,0)
        const f32x4 w1 = *(const f32x4*)(wc + 64);    // tap (0,1)
        const f32x4 w2 = *(const f32x4*)(wc + 128);   // tap (1,0)
        const f32x4 w3 = *(const f32x4*)(wc + 192);   // tap (1,1)
        // per-acc chain: tap0,1,2,3 within c — matches old conv3_k order
        a0 += X00[0] * w0; a0 += X00[1] * w1; a0 += X10[0] * w2; a0 += X10[1] * w3;
        a1 += X00[1] * w0; a1 += X00[2] * w1; a1 += X10[1] * w2; a1 += X10[2] * w3;
        a2 += X00[2] * w0; a2 += X00[3] * w1; a2 += X10[2] * w2; a2 += X10[3] * w3;
        a3 += X00[3] * w0; a3 += X01[0] * w1; a3 += X10[3] * w2; a3 += X11[0] * w3;
    }

    // z[n][oc][oy][ox]; guard ox < 63 (group 15 has 3 valid cols)
#pragma unroll
    for (int j = 0; j < 4; ++j) {
        int ox = ox4 + j;
        if (ox < 63) {
            const f32x4 aj = (j == 0) ? a0 : (j == 1) ? a1 : (j == 2) ? a2 : a3;
#pragma unroll
            for (int i = 0; i < 4; ++i) {
                z[(((size_t)n * 64 + og * 4 + i) * 63 + oy) * 63 + ox] = aj[i];
            }
        }
    }
}

// ---- VQ: argmin over 24 codes, z_probs (fp32), commitment loss ----
__global__ void vq_k(const float* __restrict__ z,
                     const float* __restrict__ codes,
                     const float* __restrict__ ema,
                     int* __restrict__ idxO,
                     float* __restrict__ zprobsO,
                     float* __restrict__ lossO) {
    __shared__ float cl[1536];
    __shared__ float cn[24];
    __shared__ float pr[24];
    for (int i = threadIdx.x; i < 1536; i += 256) cl[i] = codes[i];
    if (threadIdx.x < 24) pr[threadIdx.x] = ema[threadIdx.x];
    __syncthreads();
    if (threadIdx.x < 24) {
        float sm = 0.f;
        for (int c = 0; c < 64; ++c) { float v = cl[threadIdx.x * 64 + c]; sm += v * v; }
        cn[threadIdx.x] = sm;
    }
    __syncthreads();
    int t = blockIdx.x * 256 + threadIdx.x;
    float l = 0.f;
    if (t < 127008) {
        int b = t / 3969, s = t - b * 3969;
        const float* zp = z + (b * 64) * 3969 + s;
        float zv[64];
        float zn = 0.f;
#pragma unroll
        for (int c = 0; c < 64; ++c) { float v = zp[c * 3969]; zv[c] = v; zn += v * v; }
        float best = 1e30f; int bi = 0;
        for (int k = 0; k < 24; ++k) {
            float dot = 0.f;
#pragma unroll
            for (int c = 0; c < 64; ++c) dot += zv[c] * cl[k * 64 + c];
            float d = zn - 2.f * dot + cn[k];
            if (d < best) { best = d; bi = k; }
        }
        idxO[t] = bi;
        float psum = 0.f;
        for (int k = 0; k < 24; ++k) psum += pr[k];
        zprobsO[t] = pr[bi] / psum;
        for (int c = 0; c < 64; ++c) { float dd = cl[bi * 64 + c] - zv[c]; l += dd * dd; }
    }
    for (int off = 32; off; off >>= 1) l += __shfl_down(l, off, 64);
    if ((threadIdx.x & 63) == 0) atomicAdd(lossO, l);
}

// ---- D table: D[k][tap][oc] = sum_c codes[k][c] * dec_w1[oc][c][tap] ----
__global__ void dtab_k(const float* __restrict__ codes,
                       const float* __restrict__ w1,  // [512,64,2,2]
                       float* __restrict__ D) {
    int t = blockIdx.x * 256 + threadIdx.x;
    if (t >= 24 * 4 * 512) return;
    int oc = t & 511, tap = (t >> 9) & 3, k = t >> 11;
    float acc = 0.f;
    for (int c = 0; c < 64; ++c)
        acc += codes[k * 64 + c] * w1[oc * 256 + c * 4 + tap];
    D[t] = acc;
}

// ---- weight transform: wT[oc][tap][c] bf16 from w[oc][c][2][2] fp32 ----
__global__ void wt_k(const float* __restrict__ w, __hip_bfloat16* __restrict__ wT,
                     int cl2, int total) {
    int t = blockIdx.x * 256 + threadIdx.x;
    if (t >= total) return;
    int c = t & ((1 << cl2) - 1);
    int tap = (t >> cl2) & 3;
    int oc = t >> (cl2 + 2);
    wT[t] = __float2bfloat16(w[((oc << cl2) + c) * 4 + tap]);
}

// ---- dec1: codebook gather -> y1 NHWC [32][64][64][512] bf16, + gelu ----
__global__ void dec1_k(const int* __restrict__ idx,   // [32,63,63]
                       const float* __restrict__ D,   // [24][4][512]
                       __hip_bfloat16* __restrict__ y1) {
    const int pos = blockIdx.x;
    const int n = pos >> 12, rem = pos & 4095;
    const int iy = rem >> 6, ix = rem & 63;
    const int* idn = idx + n * 3969;
    const int t = threadIdx.x;
    float ax = 0.f, ay = 0.f;
#pragma unroll
    for (int tap = 0; tap < 4; ++tap) {
        int py = iy - 1 + (tap >> 1), px = ix - 1 + (tap & 1);
        if ((unsigned)py < 63u && (unsigned)px < 63u) {
            int k = idn[py * 63 + px];
            float2 v = ((const float2*)(D + (k * 4 + tap) * 512))[t];
            ax += v.x; ay += v.y;
        }
    }
    __hip_bfloat162 o;
    o.x = __float2bfloat16(gelu_exact(ax));
    o.y = __float2bfloat16(gelu_exact(ay));
    ((__hip_bfloat162*)(y1 + (size_t)pos * 512))[t] = o;
}

// ---- dec2 MFMA: C[pos][oc] = sum_k y1im2col[pos][k] * wT2[oc][k] ----
__global__ __launch_bounds__(256) void dec2_mfma(
    const __hip_bfloat16* __restrict__ y1,   // NHWC [32][64][64][512]
    const __hip_bfloat16* __restrict__ wT,   // [256][2048]
    const __hip_bfloat16* __restrict__ zp,   // zero page
    __hip_bfloat16* __restrict__ y2)         // NHWC [32][63][63][256]
{
    __shared__ __hip_bfloat16 As[128 * 32];
    __shared__ __hip_bfloat16 Bs[128 * 32];
    const int tid = threadIdx.x;
    const int wave = tid >> 6, lane = tid & 63;
    const int quad = lane >> 4, l15 = lane & 15;
    const int m0 = blockIdx.x * 128;
    const int oc0 = blockIdx.y * 128;
    const int sub = tid & 3;

    const char* pA[2];
    const char* pB[2];
#pragma unroll
    for (int j = 0; j < 2; ++j) {
        int slot = j * 64 + (tid >> 2);
        int pp = m0 + slot;
        if (pp < 127008) {
            int n = pp / 3969; int r = pp - n * 3969;
            int oy = r / 63;  int ox = r - oy * 63;
            pA[j] = (const char*)y1 + (size_t)((n * 64 + oy) * 64 + ox) * 1024 + sub * 16;
        } else {
            pA[j] = (const char*)zp;
        }
        pB[j] = (const char*)wT + (size_t)(oc0 + slot) * 4096 + sub * 16;
    }
    char* ldsA[2] = {(char*)As + wave * 1024, (char*)As + 4096 + wave * 1024};
    char* ldsB[2] = {(char*)Bs + wave * 1024, (char*)Bs + 4096 + wave * 1024};

    f32x4 acc[4][4] = {};
    const int wm = (wave & 1) * 64;
    const int wn = (wave >> 1) * 64;

#pragma unroll
    for (int tap = 0; tap < 4; ++tap) {
        const int toff = ((tap >> 1) * 64 + (tap & 1)) * 1024;
        for (int kk = 0; kk < 16; ++kk) {
            const int cb = kk * 64;
            GLL16(pA[0] + toff + cb, ldsA[0]);
            GLL16(pA[1] + toff + cb, ldsA[1]);
            GLL16(pB[0] + tap * 1024 + cb, ldsB[0]);
            GLL16(pB[1] + tap * 1024 + cb, ldsB[1]);
            __syncthreads();
            bf16x8 af[4], bf[4];
#pragma unroll
            for (int mi = 0; mi < 4; ++mi)
                af[mi] = *(const bf16x8*)((const char*)As + (wm + mi * 16 + l15) * 64 + quad * 16);
#pragma unroll
            for (int ni = 0; ni < 4; ++ni)
                bf[ni] = *(const bf16x8*)((const char*)Bs + (wn + ni * 16 + l15) * 64 + quad * 16);
#pragma unroll
            for (int mi = 0; mi < 4; ++mi)
#pragma unroll
                for (int ni = 0; ni < 4; ++ni)
                    acc[mi][ni] = __builtin_amdgcn_mfma_f32_16x16x32_bf16(
                        af[mi], bf[ni], acc[mi][ni], 0, 0, 0);
            __syncthreads();
        }
    }
#pragma unroll
    for (int mi = 0; mi < 4; ++mi)
#pragma unroll
        for (int r = 0; r < 4; ++r) {
            int pos = m0 + wm + mi * 16 + quad * 4 + r;
            if (pos < 127008) {
#pragma unroll
                for (int ni = 0; ni < 4; ++ni) {
                    int oc = oc0 + wn + ni * 16 + l15;
                    y2[(size_t)pos * 256 + oc] =
                        __float2bfloat16(gelu_exact(acc[mi][ni][r]));
                }
            }
        }
}

// ---- dec3 MFMA: C[oc][pos] = sum_k wT3[oc][k] * y2im2col[pos][k] ----
__global__ __launch_bounds__(256) void dec3_mfma(
    const __hip_bfloat16* __restrict__ y2,   // NHWC [32][63][63][256]
    const __hip_bfloat16* __restrict__ wT,   // [256][1024]
    const __hip_bfloat16* __restrict__ zp,
    float* __restrict__ out)                 // NCHW [32][256][64][64]
{
    __shared__ __hip_bfloat16 As[128 * 32];
    __shared__ __hip_bfloat16 Bs[128 * 32];
    const int tid = threadIdx.x;
    const int wave = tid >> 6, lane = tid & 63;
    const int quad = lane >> 4, l15 = lane & 15;
    const int p0 = blockIdx.x * 128;
    const int oc0 = blockIdx.y * 128;
    const int sub = tid & 3;

    const char* pW[2];
    const char* pP[4][2];
#pragma unroll
    for (int j = 0; j < 2; ++j) {
        int slot = j * 64 + (tid >> 2);
        pW[j] = (const char*)wT + (size_t)(oc0 + slot) * 2048 + sub * 16;
        int pp = p0 + slot;
        int n = pp >> 12, rem = pp & 4095;
        int OY = rem >> 6, OX = rem & 63;
#pragma unroll
        for (int tap = 0; tap < 4; ++tap) {
            int iy = OY - 1 + (tap >> 1), ix = OX - 1 + (tap & 1);
            if ((unsigned)iy < 63u && (unsigned)ix < 63u)
                pP[tap][j] = (const char*)y2 + (size_t)(n * 3969 + iy * 63 + ix) * 512 + sub * 16;
            else
                pP[tap][j] = (const char*)zp;
        }
    }
    char* ldsA[2] = {(char*)As + wave * 1024, (char*)As + 4096 + wave * 1024};
    char* ldsB[2] = {(char*)Bs + wave * 1024, (char*)Bs + 4096 + wave * 1024};

    f32x4 acc[4][4] = {};
    const int wm = (wave & 1) * 64;
    const int wn = (wave >> 1) * 64;

#pragma unroll
    for (int tap = 0; tap < 4; ++tap) {
        for (int kk = 0; kk < 8; ++kk) {
            const int cb = kk * 64;
            GLL16(pW[0] + tap * 512 + cb, ldsA[0]);
            GLL16(pW[1] + tap * 512 + cb, ldsA[1]);
            GLL16(pP[tap][0] + cb, ldsB[0]);
            GLL16(pP[tap][1] + cb, ldsB[1]);
            __syncthreads();
            bf16x8 af[4], bf[4];
#pragma unroll
            for (int mi = 0; mi < 4; ++mi)
                af[mi] = *(const bf16x8*)((const char*)As + (wm + mi * 16 + l15) * 64 + quad * 16);
#pragma unroll
            for (int ni = 0; ni < 4; ++ni)
                bf[ni] = *(const bf16x8*)((const char*)Bs + (wn + ni * 16 + l15) * 64 + quad * 16);
#pragma unroll
            for (int mi = 0; mi < 4; ++mi)
#pragma unroll
                for (int ni = 0; ni < 4; ++ni)
                    acc[mi][ni] = __builtin_amdgcn_mfma_f32_16x16x32_bf16(
                        af[mi], bf[ni], acc[mi][ni], 0, 0, 0);
            __syncthreads();
        }
    }
    const int n = p0 >> 12;
    const int posLocal0 = (p0 & 4095) + wn;
#pragma unroll
    for (int mi = 0; mi < 4; ++mi)
#pragma unroll
        for (int r = 0; r < 4; ++r) {
            int oc = oc0 + wm + mi * 16 + quad * 4 + r;
            float* orow = out + ((size_t)(n * 256 + oc) << 12);
#pragma unroll
            for (int ni = 0; ni < 4; ++ni)
                orow[posLocal0 + ni * 16 + l15] = acc[mi][ni][r];
        }
}

// ---- scalar: vq_loss = 0.25 * sum / (B*C*H*W) ----
__global__ void loss_k(const float* __restrict__ lossO, float* __restrict__ out) {
    out[0] = 0.25f * lossO[0] / 8128512.0f;
}

extern "C" void kernel_launch(void* const* d_in, const int* in_sizes, int n_in,
                              void* d_out, int out_size, void* d_ws, size_t ws_size,
                              hipStream_t stream) {
    const float* x     = (const float*)d_in[0];
    const float* ew1   = (const float*)d_in[1];
    const float* ew2   = (const float*)d_in[2];
    const float* ew3   = (const float*)d_in[3];
    const float* dw1   = (const float*)d_in[4];
    const float* dw2   = (const float*)d_in[5];
    const float* dw3   = (const float*)d_in[6];
    const float* codes = (const float*)d_in[7];
    const float* ema   = (const float*)d_in[8];
    float* out = (float*)d_out;

    char* ws = (char*)d_ws;
    float* z1   = (float*)(ws + 0);            // [32,64,128,128] f32
    float* z2   = (float*)(ws + 134217728);    // [32,64,64,64]  f32
    float* z    = (float*)(ws + 167772160);    // [32,64,63,63]  f32
    int*   idx  = (int*)  (ws + 200286208);    // [32,63,63]     i32
    float* loss = (float*)(ws + 200794240);    // accumulator
    __hip_bfloat16* zp  = (__hip_bfloat16*)(ws + 200794496);  // 69,632 B zero page
    float* D    = (float*)(ws + 200864128);    // [24,4,512] f32
    __hip_bfloat16* wT2 = (__hip_bfloat16*)(ws + 201650560);  // 1 MB [256][2048]
    __hip_bfloat16* wT3 = (__hip_bfloat16*)(ws + 202699136);  // 512 KB [256][1024]
    float* wt3f = (float*)(ws + 203223424);    // 64 KB [64][4][64] conv3 w
    // encoder-phase scratch overlapping decoder weight regions (dead until wt_k):
    float* wt2f = (float*)(ws + 201650560);    // 409,600 B [64][25][64]
    float* wt1f = (float*)(ws + 202699136);    //  19,200 B [3][25][64]
    __hip_bfloat16* y1  = (__hip_bfloat16*)(ws + 0);          // reuse z1
    __hip_bfloat16* y2  = (__hip_bfloat16*)(ws + 134217728);  // reuse z2+z

    hipMemsetAsync(loss, 0, 4, stream);
    hipMemsetAsync(zp, 0, 69632, stream);

    wtf_k<<<dim3(19), 256, 0, stream>>>(ew1, wt1f, 3, 4800);
    wtf_k<<<dim3(400), 256, 0, stream>>>(ew2, wt2f, 64, 102400);
    wtf3_k<<<dim3(64), 256, 0, stream>>>(ew3, wt3f);
    conv5s2_t<3, 256, 256><<<dim3(8, 8, 32), 256, 0, stream>>>(x, wt1f, z1);
    conv5s2_g<64, 128, 128><<<dim3(4, 8, 32), 256, 0, stream>>>(z1, wt2f, z2);
    conv3_t<<<dim3(63, 32), 256, 0, stream>>>(z2, wt3f, z);
    vq_k<<<dim3(497), 256, 0, stream>>>(z, codes, ema, idx, out + 33554432, loss);
    dtab_k<<<dim3(192), 256, 0, stream>>>(codes, dw1, D);
    wt_k<<<dim3(2048), 256, 0, stream>>>(dw2, wT2, 9, 524288);
    wt_k<<<dim3(1024), 256, 0, stream>>>(dw3, wT3, 8, 262144);
    dec1_k<<<dim3(131072), 256, 0, stream>>>(idx, D, y1);
    dec2_mfma<<<dim3(993, 2), 256, 0, stream>>>(y1, wT2, zp, y2);
    dec3_mfma<<<dim3(1024, 2), 256, 0, stream>>>(y2, wT3, zp, out);
    loss_k<<<1, 1, 0, stream>>>(loss, out + 33681440);
}

// Round 11
// 1158.337 us; speedup vs baseline: 2.2311x; 1.0022x over previous
//
#include <hip/hip_runtime.h>
#include <hip/hip_bf16.h>

// ---------------------------------------------------------------------------
// BottleneckVQa. Encoder fp32 (argmin stability; summation order preserved).
// conv1: r0 tiled-LDS direct conv. conv2: r6 conv5s2_g (accepted plateau,
// 393us). conv3: conv3_t LDS-slab (r10, verified). Round 11: overhead
// consolidation — dec1 batched to 2048 blocks x 64 contiguous positions
// (was 131072 tiny blocks; G11 dispatch cap), setup fused 8 launches -> 2.
// All math bitwise-preserved. VQ; MFMA bf16 decoder.
// ---------------------------------------------------------------------------

#define DEV_INLINE __device__ __forceinline__

typedef __attribute__((ext_vector_type(8))) short bf16x8;
typedef __attribute__((ext_vector_type(4))) float f32x4;

#define GLL16(g, l) __builtin_amdgcn_global_load_lds(                      \
    (const __attribute__((address_space(1))) void*)(g),                    \
    (__attribute__((address_space(3))) void*)(l), 16, 0, 0)

DEV_INLINE float gelu_exact(float v) {
    return 0.5f * v * (1.0f + erff(v * 0.70710678118654752440f));
}

// ---- setup1: wt1f + wt2f + wt3f transposes, zp zero, loss zero ----
// (replaces wtf_k x2, wtf3_k, 2 memsets; indexing verbatim from originals)
__global__ void setup1_k(const float* __restrict__ ew1,
                         const float* __restrict__ ew2,
                         const float* __restrict__ ew3,
                         float* __restrict__ wt1f,
                         float* __restrict__ wt2f,
                         float* __restrict__ wt3f,
                         unsigned short* __restrict__ zp,
                         float* __restrict__ loss) {
    int t = blockIdx.x * 256 + threadIdx.x;
    if (t < 4800) {                       // wt1f[c][tap][oc], C=3
        int oc = t & 63, rest = t >> 6;
        int tap = rest % 25, c = rest / 25;
        wt1f[t] = ew1[(oc * 3 + c) * 25 + tap];
    } else if (t < 107200) {              // wt2f[c][tap][oc], C=64
        int u = t - 4800;
        int oc = u & 63, rest = u >> 6;
        int tap = rest % 25, c = rest / 25;
        wt2f[u] = ew2[(oc * 64 + c) * 25 + tap];
    } else if (t < 123584) {              // wt3f[c][tap][oc]
        int u = t - 107200;
        int oc = u & 63, tap = (u >> 6) & 3, c = u >> 8;
        wt3f[u] = ew3[(oc * 64 + c) * 4 + tap];
    } else if (t < 158400) {              // zp: 34816 bf16 zeros (69632 B)
        zp[t - 123584] = 0;
    } else if (t == 158400) {             // loss accumulator zero
        loss[0] = 0.f;
    }
}

// ---- setup2: D table + wT2 + wT3 (replaces dtab_k, wt_k x2) ----
// Must run after conv1/conv2 (wT3/wT2 regions alias wt1f/wt2f scratch).
__global__ void setup2_k(const float* __restrict__ codes,
                         const float* __restrict__ dw1,
                         const float* __restrict__ dw2,
                         const float* __restrict__ dw3,
                         float* __restrict__ D,
                         __hip_bfloat16* __restrict__ wT2,
                         __hip_bfloat16* __restrict__ wT3) {
    int t = blockIdx.x * 256 + threadIdx.x;
    if (t < 49152) {                      // D[k][tap][oc]
        int oc = t & 511, tap = (t >> 9) & 3, k = t >> 11;
        float acc = 0.f;
        for (int c = 0; c < 64; ++c)
            acc += codes[k * 64 + c] * dw1[oc * 256 + c * 4 + tap];
        D[t] = acc;
    } else if (t < 573440) {              // wT2: cl2=9
        int u = t - 49152;
        int c = u & 511, tap = (u >> 9) & 3, oc = u >> 11;
        wT2[u] = __float2bfloat16(dw2[((oc << 9) + c) * 4 + tap]);
    } else if (t < 835584) {              // wT3: cl2=8
        int u = t - 573440;
        int c = u & 255, tap = (u >> 8) & 3, oc = u >> 10;
        wT3[u] = __float2bfloat16(dw3[((oc << 8) + c) * 4 + tap]);
    }
}

// ---- conv k5 s2 p2 + gelu, 64 oc (conv1: 2x2 pos x 16 oc, r0 variant) ----
template<int C, int IH, int IW>
__global__ __launch_bounds__(256) void conv5s2_t(
    const float* __restrict__ xg,
    const float* __restrict__ wt,   // [C][25][64]
    float* __restrict__ outg) {     // [32][64][IH/2][IW/2]
    constexpr int OH = IH / 2, OW = IW / 2;
    __shared__ float xin[35 * 36];
    __shared__ float wl[1600];
    const int tid = threadIdx.x;
    const int n = blockIdx.z;
    const int OY0 = blockIdx.y * 16, OX0 = blockIdx.x * 16;
    const int IY0 = OY0 * 2 - 2, IX0 = OX0 * 2 - 2;
    const int og = tid & 3;          // oc group: oc = og*16 + q*4 + {0..3}
    const int pg = tid >> 2;         // 64 position groups (8x8 of 2x2)
    const int py = (pg >> 3) * 2, px = (pg & 7) * 2;
    const int ry = py * 2, rx = px * 2;  // input-local base

    f32x4 a00 = {0,0,0,0}, a01 = a00, a02 = a00, a03 = a00;
    f32x4 a10 = a00, a11 = a00, a12 = a00, a13 = a00;
    f32x4 a20 = a00, a21 = a00, a22 = a00, a23 = a00;
    f32x4 a30 = a00, a31 = a00, a32 = a00, a33 = a00;

    const float* xn = xg + (size_t)n * C * IH * IW;
    for (int c = 0; c < C; ++c) {
        {   // stage weights for channel c: 1600 floats
            const float4* wsrc = (const float4*)(wt + c * 1600);
            float4* wdst = (float4*)wl;
            wdst[tid] = wsrc[tid];
            if (tid < 144) wdst[256 + tid] = wsrc[256 + tid];
        }
        const float* zc = xn + (size_t)c * IH * IW;
        for (int i = tid; i < 1225; i += 256) {
            int r = i / 35, cl = i - r * 35;
            int iy = IY0 + r, ix = IX0 + cl;
            float v = 0.f;
            if ((unsigned)iy < (unsigned)IH && (unsigned)ix < (unsigned)IW)
                v = zc[(size_t)iy * IW + ix];
            xin[r * 36 + cl] = v;
        }
        __syncthreads();
#pragma unroll
        for (int ky = 0; ky < 5; ++ky) {
            const float* r0 = xin + (ry + ky) * 36 + rx;
            const float* r1 = r0 + 72;
#pragma unroll
            for (int kx = 0; kx < 5; ++kx) {
                const f32x4* wq = (const f32x4*)(wl + (ky * 5 + kx) * 64 + og * 16);
                f32x4 w0 = wq[0], w1 = wq[1], w2 = wq[2], w3 = wq[3];
                float xA = r0[kx], xB = r0[kx + 2];
                float xC = r1[kx], xD = r1[kx + 2];
                a00 += xA * w0; a01 += xA * w1; a02 += xA * w2; a03 += xA * w3;
                a10 += xB * w0; a11 += xB * w1; a12 += xB * w2; a13 += xB * w3;
                a20 += xC * w0; a21 += xC * w1; a22 += xC * w2; a23 += xC * w3;
                a30 += xD * w0; a31 += xD * w1; a32 += xD * w2; a33 += xD * w3;
            }
        }
        __syncthreads();
    }
    const int ocb = og * 16;
#define CSTORE(v, oy, ox, q) {                                                \
        float* o = outg + (((size_t)n * 64 + ocb + (q) * 4) * OH + (oy)) * OW \
                   + (ox);                                                    \
        o[0]               = gelu_exact((v).x);                               \
        o[(size_t)OH * OW]     = gelu_exact((v).y);                           \
        o[(size_t)2 * OH * OW] = gelu_exact((v).z);                           \
        o[(size_t)3 * OH * OW] = gelu_exact((v).w); }
    CSTORE(a00, OY0 + py,     OX0 + px,     0); CSTORE(a01, OY0 + py,     OX0 + px,     1);
    CSTORE(a02, OY0 + py,     OX0 + px,     2); CSTORE(a03, OY0 + py,     OX0 + px,     3);
    CSTORE(a10, OY0 + py,     OX0 + px + 1, 0); CSTORE(a11, OY0 + py,     OX0 + px + 1, 1);
    CSTORE(a12, OY0 + py,     OX0 + px + 1, 2); CSTORE(a13, OY0 + py,     OX0 + px + 1, 3);
    CSTORE(a20, OY0 + py + 1, OX0 + px,     0); CSTORE(a21, OY0 + py + 1, OX0 + px,     1);
    CSTORE(a22, OY0 + py + 1, OX0 + px,     2); CSTORE(a23, OY0 + py + 1, OX0 + px,     3);
    CSTORE(a30, OY0 + py + 1, OX0 + px + 1, 0); CSTORE(a31, OY0 + py + 1, OX0 + px + 1, 1);
    CSTORE(a32, OY0 + py + 1, OX0 + px + 1, 2); CSTORE(a33, OY0 + py + 1, OX0 + px + 1, 3);
#undef CSTORE
}

// ---- conv2: r6 conv5s2_g (bench-verified 393us) ----
template<int C, int IH, int IW>
__global__ __launch_bounds__(256, 4) void conv5s2_g(
    const float* __restrict__ xg,
    const float* __restrict__ wt,   // [C][25][64]
    float* __restrict__ outg) {     // [32][64][IH/2][IW/2]
    constexpr int OH = IH / 2, OW = IW / 2;
    __shared__ float xp[760];        // [2 planes][19 rows][20 cols]
    const int tid = threadIdx.x;
    const int n = blockIdx.z;
    const int OY0 = blockIdx.y * 8, OX0 = blockIdx.x * 16;
    const int IY0 = OY0 * 2 - 2, IX0 = OX0 * 2 - 2;
    const int og = tid & 15;         // oc = og*4 + j
    const int pg = tid >> 4;         // 16 groups: row-pair (pg>>2), col (pg&3)
    const int py = (pg >> 2) * 2;    // out row base {0,2,4,6}
    const int px = (pg & 3) * 4;     // out col base {0,4,8,12}
    const int ry = py * 2;           // input-local row base {0,4,8,12}

    // hoisted staging slots: 684 elements (19 rows x 36 cols), 3 per thread
    int  sG[3]; int sL[3]; bool sIn[3]; bool sWr[3];
#pragma unroll
    for (int k = 0; k < 3; ++k) {
        int s = tid + k * 256;
        int r = s / 36, cl = s - r * 36;
        int iy = IY0 + r, ix = IX0 + cl;
        sWr[k] = (s < 684);
        sIn[k] = sWr[k] && ((unsigned)iy < (unsigned)IH) &&
                 ((unsigned)ix < (unsigned)IW);
        sG[k] = sIn[k] ? (iy * IW + ix) : 0;
        sL[k] = sWr[k] ? ((cl & 1) * 380 + r * 20 + (cl >> 1)) : 0;
    }

    const float* xn = xg + (size_t)n * C * IH * IW;
    const float* wtb = wt + og * 4;  // per-lane weight base (oc offset)

    f32x4 a00 = {0,0,0,0}, a01 = a00, a02 = a00, a03 = a00;
    f32x4 a10 = a00, a11 = a00, a12 = a00, a13 = a00;

    for (int c = 0; c < C; ++c) {
        const float* zc = xn + (size_t)c * IH * IW;
#pragma unroll
        for (int k = 0; k < 3; ++k) {
            if (sWr[k]) {
                float v = sIn[k] ? zc[sG[k]] : 0.f;
                xp[sL[k]] = v;
            }
        }
        __syncthreads();

        const float* wc = wtb + (size_t)c * 1600;   // [25][64] this channel
#define PICK8(Qa, Qb, i) ((i) < 4 ? (Qa)[(i) & 3] : (Qb)[(i) & 3])
#define XV(R, kx, jj) (((kx) & 1)                                           \
        ? PICK8(O##R##0, O##R##1, (jj) + ((kx) >> 1))                       \
        : PICK8(E##R##0, E##R##1, (jj) + ((kx) >> 1)))
#pragma unroll
        for (int ky = 0; ky < 5; ++ky) {
            // weights for this ky: 5 taps, one f32x4 each (global, L2-hit)
            f32x4 w0 = *(const f32x4*)(wc + (ky * 5 + 0) * 64);
            f32x4 w1 = *(const f32x4*)(wc + (ky * 5 + 1) * 64);
            f32x4 w2 = *(const f32x4*)(wc + (ky * 5 + 2) * 64);
            f32x4 w3 = *(const f32x4*)(wc + (ky * 5 + 3) * 64);
            f32x4 w4 = *(const f32x4*)(wc + (ky * 5 + 4) * 64);
            // x quads for rows R0 = ry+ky, R1 = R0+2, both parity planes
            const float* e0 = xp + (ry + ky) * 20 + px;
            const float* o0 = e0 + 380;
            const float* e1 = e0 + 40;
            const float* o1 = o0 + 40;
            const f32x4 E00 = *(const f32x4*)e0, E01 = *(const f32x4*)(e0 + 4);
            const f32x4 O00 = *(const f32x4*)o0, O01 = *(const f32x4*)(o0 + 4);
            const f32x4 E10 = *(const f32x4*)e1, E11 = *(const f32x4*)(e1 + 4);
            const f32x4 O10 = *(const f32x4*)o1, O11 = *(const f32x4*)(o1 + 4);
#pragma unroll
            for (int kx = 0; kx < 5; ++kx) {
                const f32x4 wv = (kx == 0) ? w0 : (kx == 1) ? w1
                               : (kx == 2) ? w2 : (kx == 3) ? w3 : w4;
                float xA = XV(0, kx, 0), xB = XV(0, kx, 1);
                float xC = XV(0, kx, 2), xD = XV(0, kx, 3);
                float xE = XV(1, kx, 0), xF = XV(1, kx, 1);
                float xG = XV(1, kx, 2), xH = XV(1, kx, 3);
                a00 += xA * wv; a01 += xB * wv; a02 += xC * wv; a03 += xD * wv;
                a10 += xE * wv; a11 += xF * wv; a12 += xG * wv; a13 += xH * wv;
            }
        }
#undef XV
#undef PICK8
        __syncthreads();
    }

    const size_t HW = (size_t)OH * OW;
#pragma unroll
    for (int j = 0; j < 4; ++j) {
        float* o = outg + ((size_t)n * 64 + og * 4 + j) * HW
                   + (size_t)(OY0 + py) * OW + (OX0 + px);
        f32x4 t0, t1;
        t0[0] = gelu_exact(a00[j]); t0[1] = gelu_exact(a01[j]);
        t0[2] = gelu_exact(a02[j]); t0[3] = gelu_exact(a03[j]);
        t1[0] = gelu_exact(a10[j]); t1[1] = gelu_exact(a11[j]);
        t1[2] = gelu_exact(a12[j]); t1[3] = gelu_exact(a13[j]);
        *(f32x4*)o = t0;
        *(f32x4*)(o + OW) = t1;
    }
}

// ---- conv3_t: [32,64,64,64] -> [32,64,63,63], k2 s1 p0, fp32 (r10) ----
__global__ __launch_bounds__(256) void conv3_t(
    const float* __restrict__ z2,
    const float* __restrict__ wt3,   // [64][4][64] fp32
    float* __restrict__ z) {         // [32][64][63][63]
    __shared__ float xs[64 * 144];   // [c][2 rows][72 cols]
    const int tid = threadIdx.x;
    const int oy = blockIdx.x;       // 0..62
    const int n  = blockIdx.y;

    {   // stage x-slab: 2048 f32x4, 8 per thread (coalesced 64B runs)
        const float* zn = z2 + (size_t)n * 64 * 4096 + oy * 64;
#pragma unroll
        for (int k = 0; k < 8; ++k) {
            int fid = tid + k * 256;
            int c = fid >> 5, rem = fid & 31;
            int r = rem >> 4, q = rem & 15;
            f32x4 v = *(const f32x4*)(zn + c * 4096 + r * 64 + q * 4);
            *(f32x4*)(xs + c * 144 + r * 72 + q * 4) = v;
        }
    }
    __syncthreads();

    const int og  = tid >> 4;        // 0..15 -> oc = og*4 + {0..3}
    const int ox4 = (tid & 15) * 4;  // 0,4,...,60
    f32x4 a0 = {0,0,0,0}, a1 = a0, a2 = a0, a3 = a0;   // ox4+0..3
    const float* wb = wt3 + og * 4;

    for (int c = 0; c < 64; ++c) {
        const float* xc = xs + c * 144 + ox4;
        const f32x4 X00 = *(const f32x4*)(xc);
        const f32x4 X01 = *(const f32x4*)(xc + 4);
        const f32x4 X10 = *(const f32x4*)(xc + 72);
        const f32x4 X11 = *(const f32x4*)(xc + 76);
        const float* wc = wb + c * 256;
        const f32x4 w0 = *(const f32x4*)(wc);
        const f32x4 w1 = *(const f32x4*)(wc + 64);
        const f32x4 w2 = *(const f32x4*)(wc + 128);
        const f32x4 w3 = *(const f32x4*)(wc + 192);
        a0 += X00[0] * w0; a0 += X00[1] * w1; a0 += X10[0] * w2; a0 += X10[1] * w3;
        a1 += X00[1] * w0; a1 += X00[2] * w1; a1 += X10[1] * w2; a1 += X10[2] * w3;
        a2 += X00[2] * w0; a2 += X00[3] * w1; a2 += X10[2] * w2; a2 += X10[3] * w3;
        a3 += X00[3] * w0; a3 += X01[0] * w1; a3 += X10[3] * w2; a3 += X11[0] * w3;
    }

#pragma unroll
    for (int j = 0; j < 4; ++j) {
        int ox = ox4 + j;
        if (ox < 63) {
            const f32x4 aj = (j == 0) ? a0 : (j == 1) ? a1 : (j == 2) ? a2 : a3;
#pragma unroll
            for (int i = 0; i < 4; ++i) {
                z[(((size_t)n * 64 + og * 4 + i) * 63 + oy) * 63 + ox] = aj[i];
            }
        }
    }
}

// ---- VQ: argmin over 24 codes, z_probs (fp32), commitment loss ----
__global__ void vq_k(const float* __restrict__ z,
                     const float* __restrict__ codes,
                     const float* __restrict__ ema,
                     int* __restrict__ idxO,
                     float* __restrict__ zprobsO,
                     float* __restrict__ lossO) {
    __shared__ float cl[1536];
    __shared__ float cn[24];
    __shared__ float pr[24];
    for (int i = threadIdx.x; i < 1536; i += 256) cl[i] = codes[i];
    if (threadIdx.x < 24) pr[threadIdx.x] = ema[threadIdx.x];
    __syncthreads();
    if (threadIdx.x < 24) {
        float sm = 0.f;
        for (int c = 0; c < 64; ++c) { float v = cl[threadIdx.x * 64 + c]; sm += v * v; }
        cn[threadIdx.x] = sm;
    }
    __syncthreads();
    int t = blockIdx.x * 256 + threadIdx.x;
    float l = 0.f;
    if (t < 127008) {
        int b = t / 3969, s = t - b * 3969;
        const float* zp = z + (b * 64) * 3969 + s;
        float zv[64];
        float zn = 0.f;
#pragma unroll
        for (int c = 0; c < 64; ++c) { float v = zp[c * 3969]; zv[c] = v; zn += v * v; }
        float best = 1e30f; int bi = 0;
        for (int k = 0; k < 24; ++k) {
            float dot = 0.f;
#pragma unroll
            for (int c = 0; c < 64; ++c) dot += zv[c] * cl[k * 64 + c];
            float d = zn - 2.f * dot + cn[k];
            if (d < best) { best = d; bi = k; }
        }
        idxO[t] = bi;
        float psum = 0.f;
        for (int k = 0; k < 24; ++k) psum += pr[k];
        zprobsO[t] = pr[bi] / psum;
        for (int c = 0; c < 64; ++c) { float dd = cl[bi * 64 + c] - zv[c]; l += dd * dd; }
    }
    for (int off = 32; off; off >>= 1) l += __shfl_down(l, off, 64);
    if ((threadIdx.x & 63) == 0) atomicAdd(lossO, l);
}

// ---- dec1_g: codebook gather -> y1 NHWC bf16 + gelu; 2048 blocks x 64
// contiguous positions (was 131072 one-position blocks; per-position math
// and store identical -> y1 bitwise unchanged; block span = one ix row so
// idn/D rows are L1-reused). ----
__global__ __launch_bounds__(256) void dec1_g(
    const int* __restrict__ idx,   // [32,63,63]
    const float* __restrict__ D,   // [24][4][512]
    __hip_bfloat16* __restrict__ y1) {
    const int t = threadIdx.x;
    const int base = blockIdx.x * 64;
    for (int q = 0; q < 64; ++q) {
        const int pos = base + q;
        const int n = pos >> 12, rem = pos & 4095;
        const int iy = rem >> 6, ix = rem & 63;
        const int* idn = idx + n * 3969;
        float ax = 0.f, ay = 0.f;
#pragma unroll
        for (int tap = 0; tap < 4; ++tap) {
            int py = iy - 1 + (tap >> 1), px = ix - 1 + (tap & 1);
            if ((unsigned)py < 63u && (unsigned)px < 63u) {
                int k = idn[py * 63 + px];
                float2 v = ((const float2*)(D + (k * 4 + tap) * 512))[t];
                ax += v.x; ay += v.y;
            }
        }
        __hip_bfloat162 o;
        o.x = __float2bfloat16(gelu_exact(ax));
        o.y = __float2bfloat16(gelu_exact(ay));
        ((__hip_bfloat162*)(y1 + (size_t)pos * 512))[t] = o;
    }
}

// ---- dec2 MFMA: C[pos][oc] = sum_k y1im2col[pos][k] * wT2[oc][k] ----
__global__ __launch_bounds__(256) void dec2_mfma(
    const __hip_bfloat16* __restrict__ y1,   // NHWC [32][64][64][512]
    const __hip_bfloat16* __restrict__ wT,   // [256][2048]
    const __hip_bfloat16* __restrict__ zp,   // zero page
    __hip_bfloat16* __restrict__ y2)         // NHWC [32][63][63][256]
{
    __shared__ __hip_bfloat16 As[128 * 32];
    __shared__ __hip_bfloat16 Bs[128 * 32];
    const int tid = threadIdx.x;
    const int wave = tid >> 6, lane = tid & 63;
    const int quad = lane >> 4, l15 = lane & 15;
    const int m0 = blockIdx.x * 128;
    const int oc0 = blockIdx.y * 128;
    const int sub = tid & 3;

    const char* pA[2];
    const char* pB[2];
#pragma unroll
    for (int j = 0; j < 2; ++j) {
        int slot = j * 64 + (tid >> 2);
        int pp = m0 + slot;
        if (pp < 127008) {
            int n = pp / 3969; int r = pp - n * 3969;
            int oy = r / 63;  int ox = r - oy * 63;
            pA[j] = (const char*)y1 + (size_t)((n * 64 + oy) * 64 + ox) * 1024 + sub * 16;
        } else {
            pA[j] = (const char*)zp;
        }
        pB[j] = (const char*)wT + (size_t)(oc0 + slot) * 4096 + sub * 16;
    }
    char* ldsA[2] = {(char*)As + wave * 1024, (char*)As + 4096 + wave * 1024};
    char* ldsB[2] = {(char*)Bs + wave * 1024, (char*)Bs + 4096 + wave * 1024};

    f32x4 acc[4][4] = {};
    const int wm = (wave & 1) * 64;
    const int wn = (wave >> 1) * 64;

#pragma unroll
    for (int tap = 0; tap < 4; ++tap) {
        const int toff = ((tap >> 1) * 64 + (tap & 1)) * 1024;
        for (int kk = 0; kk < 16; ++kk) {
            const int cb = kk * 64;
            GLL16(pA[0] + toff + cb, ldsA[0]);
            GLL16(pA[1] + toff + cb, ldsA[1]);
            GLL16(pB[0] + tap * 1024 + cb, ldsB[0]);
            GLL16(pB[1] + tap * 1024 + cb, ldsB[1]);
            __syncthreads();
            bf16x8 af[4], bf[4];
#pragma unroll
            for (int mi = 0; mi < 4; ++mi)
                af[mi] = *(const bf16x8*)((const char*)As + (wm + mi * 16 + l15) * 64 + quad * 16);
#pragma unroll
            for (int ni = 0; ni < 4; ++ni)
                bf[ni] = *(const bf16x8*)((const char*)Bs + (wn + ni * 16 + l15) * 64 + quad * 16);
#pragma unroll
            for (int mi = 0; mi < 4; ++mi)
#pragma unroll
                for (int ni = 0; ni < 4; ++ni)
                    acc[mi][ni] = __builtin_amdgcn_mfma_f32_16x16x32_bf16(
                        af[mi], bf[ni], acc[mi][ni], 0, 0, 0);
            __syncthreads();
        }
    }
#pragma unroll
    for (int mi = 0; mi < 4; ++mi)
#pragma unroll
        for (int r = 0; r < 4; ++r) {
            int pos = m0 + wm + mi * 16 + quad * 4 + r;
            if (pos < 127008) {
#pragma unroll
                for (int ni = 0; ni < 4; ++ni) {
                    int oc = oc0 + wn + ni * 16 + l15;
                    y2[(size_t)pos * 256 + oc] =
                        __float2bfloat16(gelu_exact(acc[mi][ni][r]));
                }
            }
        }
}

// ---- dec3 MFMA: C[oc][pos] = sum_k wT3[oc][k] * y2im2col[pos][k] ----
__global__ __launch_bounds__(256) void dec3_mfma(
    const __hip_bfloat16* __restrict__ y2,   // NHWC [32][63][63][256]
    const __hip_bfloat16* __restrict__ wT,   // [256][1024]
    const __hip_bfloat16* __restrict__ zp,
    float* __restrict__ out)                 // NCHW [32][256][64][64]
{
    __shared__ __hip_bfloat16 As[128 * 32];
    __shared__ __hip_bfloat16 Bs[128 * 32];
    const int tid = threadIdx.x;
    const int wave = tid >> 6, lane = tid & 63;
    const int quad = lane >> 4, l15 = lane & 15;
    const int p0 = blockIdx.x * 128;
    const int oc0 = blockIdx.y * 128;
    const int sub = tid & 3;

    const char* pW[2];
    const char* pP[4][2];
#pragma unroll
    for (int j = 0; j < 2; ++j) {
        int slot = j * 64 + (tid >> 2);
        pW[j] = (const char*)wT + (size_t)(oc0 + slot) * 2048 + sub * 16;
        int pp = p0 + slot;
        int n = pp >> 12, rem = pp & 4095;
        int OY = rem >> 6, OX = rem & 63;
#pragma unroll
        for (int tap = 0; tap < 4; ++tap) {
            int iy = OY - 1 + (tap >> 1), ix = OX - 1 + (tap & 1);
            if ((unsigned)iy < 63u && (unsigned)ix < 63u)
                pP[tap][j] = (const char*)y2 + (size_t)(n * 3969 + iy * 63 + ix) * 512 + sub * 16;
            else
                pP[tap][j] = (const char*)zp;
        }
    }
    char* ldsA[2] = {(char*)As + wave * 1024, (char*)As + 4096 + wave * 1024};
    char* ldsB[2] = {(char*)Bs + wave * 1024, (char*)Bs + 4096 + wave * 1024};

    f32x4 acc[4][4] = {};
    const int wm = (wave & 1) * 64;
    const int wn = (wave >> 1) * 64;

#pragma unroll
    for (int tap = 0; tap < 4; ++tap) {
        for (int kk = 0; kk < 8; ++kk) {
            const int cb = kk * 64;
            GLL16(pW[0] + tap * 512 + cb, ldsA[0]);
            GLL16(pW[1] + tap * 512 + cb, ldsA[1]);
            GLL16(pP[tap][0] + cb, ldsB[0]);
            GLL16(pP[tap][1] + cb, ldsB[1]);
            __syncthreads();
            bf16x8 af[4], bf[4];
#pragma unroll
            for (int mi = 0; mi < 4; ++mi)
                af[mi] = *(const bf16x8*)((const char*)As + (wm + mi * 16 + l15) * 64 + quad * 16);
#pragma unroll
            for (int ni = 0; ni < 4; ++ni)
                bf[ni] = *(const bf16x8*)((const char*)Bs + (wn + ni * 16 + l15) * 64 + quad * 16);
#pragma unroll
            for (int mi = 0; mi < 4; ++mi)
#pragma unroll
                for (int ni = 0; ni < 4; ++ni)
                    acc[mi][ni] = __builtin_amdgcn_mfma_f32_16x16x32_bf16(
                        af[mi], bf[ni], acc[mi][ni], 0, 0, 0);
            __syncthreads();
        }
    }
    const int n = p0 >> 12;
    const int posLocal0 = (p0 & 4095) + wn;
#pragma unroll
    for (int mi = 0; mi < 4; ++mi)
#pragma unroll
        for (int r = 0; r < 4; ++r) {
            int oc = oc0 + wm + mi * 16 + quad * 4 + r;
            float* orow = out + ((size_t)(n * 256 + oc) << 12);
#pragma unroll
            for (int ni = 0; ni < 4; ++ni)
                orow[posLocal0 + ni * 16 + l15] = acc[mi][ni][r];
        }
}

// ---- scalar: vq_loss = 0.25 * sum / (B*C*H*W) ----
__global__ void loss_k(const float* __restrict__ lossO, float* __restrict__ out) {
    out[0] = 0.25f * lossO[0] / 8128512.0f;
}

extern "C" void kernel_launch(void* const* d_in, const int* in_sizes, int n_in,
                              void* d_out, int out_size, void* d_ws, size_t ws_size,
                              hipStream_t stream) {
    const float* x     = (const float*)d_in[0];
    const float* ew1   = (const float*)d_in[1];
    const float* ew2   = (const float*)d_in[2];
    const float* ew3   = (const float*)d_in[3];
    const float* dw1   = (const float*)d_in[4];
    const float* dw2   = (const float*)d_in[5];
    const float* dw3   = (const float*)d_in[6];
    const float* codes = (const float*)d_in[7];
    const float* ema   = (const float*)d_in[8];
    float* out = (float*)d_out;

    char* ws = (char*)d_ws;
    float* z1   = (float*)(ws + 0);            // [32,64,128,128] f32
    float* z2   = (float*)(ws + 134217728);    // [32,64,64,64]  f32
    float* z    = (float*)(ws + 167772160);    // [32,64,63,63]  f32
    int*   idx  = (int*)  (ws + 200286208);    // [32,63,63]     i32
    float* loss = (float*)(ws + 200794240);    // accumulator
    __hip_bfloat16* zp  = (__hip_bfloat16*)(ws + 200794496);  // 69,632 B zero page
    float* D    = (float*)(ws + 200864128);    // [24,4,512] f32
    __hip_bfloat16* wT2 = (__hip_bfloat16*)(ws + 201650560);  // 1 MB [256][2048]
    __hip_bfloat16* wT3 = (__hip_bfloat16*)(ws + 202699136);  // 512 KB [256][1024]
    float* wt3f = (float*)(ws + 203223424);    // 64 KB [64][4][64] conv3 w
    // encoder-phase scratch overlapping decoder weight regions (dead until setup2):
    float* wt2f = (float*)(ws + 201650560);    // 409,600 B [64][25][64]
    float* wt1f = (float*)(ws + 202699136);    //  19,200 B [3][25][64]
    __hip_bfloat16* y1  = (__hip_bfloat16*)(ws + 0);          // reuse z1
    __hip_bfloat16* y2  = (__hip_bfloat16*)(ws + 134217728);  // reuse z2+z

    // setup1: weight transposes + zp/loss zero (replaces 3 kernels + 2 memsets)
    setup1_k<<<dim3(620), 256, 0, stream>>>(ew1, ew2, ew3, wt1f, wt2f, wt3f,
                                            (unsigned short*)zp, loss);
    conv5s2_t<3, 256, 256><<<dim3(8, 8, 32), 256, 0, stream>>>(x, wt1f, z1);
    conv5s2_g<64, 128, 128><<<dim3(4, 8, 32), 256, 0, stream>>>(z1, wt2f, z2);
    conv3_t<<<dim3(63, 32), 256, 0, stream>>>(z2, wt3f, z);
    vq_k<<<dim3(497), 256, 0, stream>>>(z, codes, ema, idx, out + 33554432, loss);
    // setup2: D + wT2 + wT3 (after convs: regions alias encoder scratch)
    setup2_k<<<dim3(3264), 256, 0, stream>>>(codes, dw1, dw2, dw3, D, wT2, wT3);
    dec1_g<<<dim3(2048), 256, 0, stream>>>(idx, D, y1);
    dec2_mfma<<<dim3(993, 2), 256, 0, stream>>>(y1, wT2, zp, y2);
    dec3_mfma<<<dim3(1024, 2), 256, 0, stream>>>(y2, wT3, zp, out);
    loss_k<<<1, 1, 0, stream>>>(loss, out + 33681440);
}